// Round 1
// 95.883 us; speedup vs baseline: 1.0214x; 1.0214x over previous
//
#include <hip/hip_runtime.h>
#include <math.h>

// Dims
#define IMG 64
#define NPIX 4096      // 64*64 pixels, px = ix*64 + iy
#define NSLICE 16
#define NCOIL 4
#define NSING 4
#define NECHO 3
#define NRO 32
#define NPT 96
#define NEC 12         // NECHO*NCOIL after ur-contraction

typedef float v2f __attribute__((ext_vector_type(2)));

// ws layout: ex2 table [32r][33k][96p] float2 (811 KB), then imgw [32r][12ec][4096px] float2 (12.6 MB)
// ex2[r][k][p] = exp(-i*k*w0(r,p)) for k=1..31 ; k=0 slot holds exp(+32i*w0) (the x=0 special)
#define EXG2_F2 (NRO * 33 * NPT)          // 101376 float2

// ---------------------------------------------------------------------------
// Kernel A: imgw[r][ec][px] = sum_n ur[r,n] * DFTz(sign * sc * sm)[n,e,c, zb[r]]
// (unchanged from previous round; measured fine)
// ---------------------------------------------------------------------------
__global__ __launch_bounds__(256) void precompute_imgw(
    const float2* __restrict__ sing,   // [4096px][16z][4n][3e]
    const float2* __restrict__ smap,   // [4c][4096px][16z]
    const float*  __restrict__ ur,     // [32][4]
    const int*    __restrict__ zb,     // [32]
    const float*  __restrict__ kt,     // [32][96][2]
    float2* __restrict__ ex2,          // [32][33][96]
    float2* __restrict__ imgw)         // [32][12][4096]
{
  __shared__ float2 sc_sh[4 * 192];    // [pxl][z*12 + s]
  __shared__ float2 sm_sh[4 * 64];     // [pxl][c*16 + z]
  __shared__ float2 f_sh[4 * 48 * 16]; // [pxl][s*4+c][kz]   24 KB
  __shared__ float  ur_sh[128];
  __shared__ int    zb_sh[32];

  const int t   = threadIdx.x;
  const int px0 = blockIdx.x * 4;

  // side job: phase table (32*33*96 = 101376 = 396 blocks * 256 threads)
  if (blockIdx.x < 396) {
    int g = blockIdx.x * 256 + t;
    int p = g % 96;
    int k = (g / 96) % 33;
    int r = g / (96 * 33);
    float w0 = kt[(r * 96 + p) * 2];
    float ang = (k == 0) ? (32.0f * w0) : (-(float)k * w0);
    float s_, c_;
    __sincosf(ang, &s_, &c_);
    ex2[g] = make_float2(c_, s_);
  }

  // stage inputs (coalesced)
  for (int j = t; j < 768; j += 256) sc_sh[j] = sing[px0 * 192 + j];
  {
    int c = t >> 6, pxl = (t >> 4) & 3, z = t & 15;
    sm_sh[pxl * 64 + c * 16 + z] = smap[c * 65536 + (px0 + pxl) * 16 + z];
  }
  if (t < 128) ur_sh[t] = ur[t];
  if (t < 32)  zb_sh[t] = zb[t];
  __syncthreads();

  const int pxl = t >> 6, lane = t & 63;
  const int s = lane >> 2, c = lane & 3;

  // W16[m] = exp(-2*pi*i*m/16)
  const float wr[16] = { 1.f,  0.92387953f,  0.70710678f,  0.38268343f,
                         0.f, -0.38268343f, -0.70710678f, -0.92387953f,
                        -1.f, -0.92387953f, -0.70710678f, -0.38268343f,
                         0.f,  0.38268343f,  0.70710678f,  0.92387953f };
  const float wi_fix[16] = { 0.f, -0.38268343f, -0.70710678f, -0.92387953f,
                        -1.f, -0.92387953f, -0.70710678f, -0.38268343f,
                         0.f,  0.38268343f,  0.70710678f,  0.92387953f,
                         1.f,  0.92387953f,  0.70710678f,  0.38268343f };

  if (lane < 48) {
    float br[16], bi[16];
    #pragma unroll
    for (int z = 0; z < 16; ++z) {
      float2 a = sc_sh[pxl * 192 + z * 12 + s];
      float2 m = sm_sh[pxl * 64 + c * 16 + z];
      float sg = (z & 1) ? -1.f : 1.f;
      br[z] = sg * (a.x * m.x - a.y * m.y);
      bi[z] = sg * (a.x * m.y + a.y * m.x);
    }
    // f[kz] = E[kz&7] +/- W16[kz&7]*O[kz&7];  E/O = DFT8 of even/odd z
    float Er[8], Ei[8], Or[8], Oi[8];
    #pragma unroll
    for (int k = 0; k < 8; ++k) {
      float er = 0.f, ei = 0.f, pr = 0.f, pi = 0.f;
      #pragma unroll
      for (int m = 0; m < 8; ++m) {
        const int idx = (2 * k * m) & 15;
        er = fmaf(br[2*m],    wr[idx], er); er = fmaf(-bi[2*m],   wi_fix[idx], er);
        ei = fmaf(br[2*m],    wi_fix[idx], ei); ei = fmaf( bi[2*m],   wr[idx], ei);
        pr = fmaf(br[2*m+1],  wr[idx], pr); pr = fmaf(-bi[2*m+1], wi_fix[idx], pr);
        pi = fmaf(br[2*m+1],  wi_fix[idx], pi); pi = fmaf( bi[2*m+1], wr[idx], pi);
      }
      Er[k] = er; Ei[k] = ei; Or[k] = pr; Oi[k] = pi;
    }
    float2* frow = &f_sh[(pxl * 48 + s * 4 + c) * 16];
    #pragma unroll
    for (int k = 0; k < 8; ++k) {
      float tr = Or[k] * wr[k] - Oi[k] * wi_fix[k];
      float ti = Or[k] * wi_fix[k] + Oi[k] * wr[k];
      frow[k]     = make_float2(Er[k] + tr, Ei[k] + ti);
      frow[k + 8] = make_float2(Er[k] - tr, Ei[k] - ti);
    }
  }
  __syncthreads();

  // contraction + store: 1536 outputs (4 px * 384 rc), 6 per thread
  for (int j = t; j < 1536; j += 256) {
    int rc  = j >> 2;       // r*12 + ec
    int pl  = j & 3;
    int r   = rc / 12, ec = rc - r * 12;
    int e   = ec >> 2, cc = ec & 3;
    int kz  = zb_sh[r];
    float vr = 0.f, vi = 0.f;
    #pragma unroll
    for (int n = 0; n < 4; ++n) {
      float u  = ur_sh[r * 4 + n];
      float2 f = f_sh[(pl * 48 + (n * 3 + e) * 4 + cc) * 16 + kz];
      vr = fmaf(u, f.x, vr);
      vi = fmaf(u, f.y, vi);
    }
    imgw[rc * 4096 + px0 + pl] = make_float2(vr, vi);
  }
}

// ---------------------------------------------------------------------------
// Kernel B: one block (256 thr = 4 waves) per (r,ec,ps). Conjugate-folded
// NUFFT. R6 changes vs R5:
//  - fold happens DURING global->LDS staging, into an interleaved float4
//    (sxy.x,sxy.y,dyx.x,dyx.y) layout: no LDS round-trip, 1 barrier (was 3),
//    and the K-loop fold read is a single ds_read_b128 (was 2x b64).
//  - ev broadcasts read as 6x ds_read_b128 (was 12x b64): 7 DS instr/k (was 14).
//  - kt(w1) prefetched before the K-loop.
//  - epilogue reduce-scatter: select-before-shuffle halving of live values
//    (12->6->3->2->1), 28 cross-lane ops/thread (was 288), one scatter store
//    from 12 lanes (was 12 serialized lane-0 stores).
// ---------------------------------------------------------------------------
__global__ __launch_bounds__(256, 3) void nufft_points(
    const float*  __restrict__ kt,     // [32][96][2]
    const float2* __restrict__ ex2,    // [32][33][96]
    const float2* __restrict__ imgw,   // [32][12][4096]
    float2* __restrict__ out)          // [96][4][32][3]
{
  __shared__ float4 w2_sh[31 * 64];            // folded pairs, 31 KB
  __shared__ float2 w0_sh[64];                 // x = 0 row (k=32 special)
  __shared__ float2 w32_sh[64];                // x = 32 row (k=0 special)
  __shared__ __align__(16) float2 ex_sh[33 * 48];  // 12.4 KB

  const int bid = blockIdx.x;          // 768 = 32r * 12ec * 2ps
  const int r   = bid & 31;
  const int ec  = (bid >> 5) % 12;
  const int ps  = bid / 384;
  const int e   = ec >> 2, c = ec & 3;
  const int t    = threadIdx.x;
  const int lane = t & 63;
  const int p0l  = (t >> 6) * 12;      // local point base (0,12,24,36)
  const int p0   = ps * 48 + p0l;      // global point base

  // prefetch w1 for the epilogue (lane-uniform broadcast loads)
  float w1v[12];
  #pragma unroll
  for (int pp = 0; pp < 12; ++pp) w1v[pp] = kt[(r * 96 + p0 + pp) * 2 + 1];

  const float2* __restrict__ wsrc = imgw + (r * 12 + ec) * 4096;

  // stage the two unpaired rows (x=0 and x=32)
  if (t < 128) {
    int which = t >> 6, y = t & 63;
    float2 v = wsrc[which * 32 * 64 + y];
    if (which == 0) w0_sh[y] = v; else w32_sh[y] = v;
  }
  // conjugate-fold directly from global into interleaved (sxy,dyx) float4s
  for (int idx = t; idx < 31 * 64; idx += 256) {
    int k = 1 + (idx >> 6), y = idx & 63;
    float2 wa = wsrc[(32 + k) * 64 + y];
    float2 wb = wsrc[(32 - k) * 64 + y];
    w2_sh[idx] = make_float4(wa.x + wb.x, wa.y + wb.y,
                             -(wa.y - wb.y), wa.x - wb.x);
  }
  // stage ex slice: [k=0..32][pl=0..47]
  {
    const float2* esrc = ex2 + r * (33 * 96) + ps * 48;
    for (int idx = t; idx < 33 * 48; idx += 256) {
      int k = idx / 48, pl = idx - k * 48;
      ex_sh[idx] = esrc[k * 96 + pl];
    }
  }
  __syncthreads();

  // seed: acc[pp] = w[x=32] + w[x=0] * e^{+32i w0(p)}   (k=0 slot of ex_sh)
  v2f acc[12];
  {
    float2 w0v = w0_sh[lane];
    float2 w32 = w32_sh[lane];
    const float4* e40 = (const float4*)(ex_sh + p0l);
    #pragma unroll
    for (int pq = 0; pq < 6; ++pq) {
      float4 e2 = e40[pq];
      acc[2*pq].x   = w32.x + w0v.x * e2.x - w0v.y * e2.y;
      acc[2*pq].y   = w32.y + w0v.x * e2.y + w0v.y * e2.x;
      acc[2*pq+1].x = w32.x + w0v.x * e2.z - w0v.y * e2.w;
      acc[2*pq+1].y = w32.y + w0v.x * e2.w + w0v.y * e2.z;
    }
  }

  // hot loop: 7 DS instr per k (1 per-lane b128 + 6 broadcast b128), 24 pk_fma
  #pragma unroll 2
  for (int k = 1; k < 32; ++k) {
    float4 wv = w2_sh[(k - 1) * 64 + lane];
    v2f sxy = { wv.x, wv.y };
    v2f dyx = { wv.z, wv.w };
    const float4* e4 = (const float4*)(ex_sh + k * 48 + p0l);
    #pragma unroll
    for (int pq = 0; pq < 6; ++pq) {
      float4 e2 = e4[pq];
      acc[2*pq]   = __builtin_elementwise_fma(sxy, (v2f)(e2.x), acc[2*pq]);
      acc[2*pq]   = __builtin_elementwise_fma(dyx, (v2f)(e2.y), acc[2*pq]);
      acc[2*pq+1] = __builtin_elementwise_fma(sxy, (v2f)(e2.z), acc[2*pq+1]);
      acc[2*pq+1] = __builtin_elementwise_fma(dyx, (v2f)(e2.w), acc[2*pq+1]);
    }
  }

  // epilogue: rotate by ey(p, lane)
  const float yy = (float)(lane - 32);
  #pragma unroll
  for (int pp = 0; pp < 12; ++pp) {
    float es, ec_;
    __sincosf(-w1v[pp] * yy, &es, &ec_);
    v2f tv;
    tv.x = acc[pp].x * ec_ - acc[pp].y * es;
    tv.y = acc[pp].x * es  + acc[pp].y * ec_;
    acc[pp] = tv;
  }

  // reduce-scatter across 64 lanes. At each level, select-before-shuffle:
  //   x = bit ? B : A; y = bit ? A : B; out = x + shfl_xor(y, off)
  // sums the lane-pair while halving live values. Value identity after L4:
  //   pp = b2 ? (8 + 2*b4 + b5) : (4*b3 + 2*b4 + b5)
  const int b5 = (lane >> 5) & 1, b4 = (lane >> 4) & 1;
  const int b3 = (lane >> 3) & 1, b2 = (lane >> 2) & 1;

#define RPAIR(OUT, A, B, BIT, OFF) do {            \
    v2f x_ = (BIT) ? (B) : (A);                    \
    v2f y_ = (BIT) ? (A) : (B);                    \
    v2f s_;                                        \
    s_.x = __shfl_xor(y_.x, OFF);                  \
    s_.y = __shfl_xor(y_.y, OFF);                  \
    OUT = x_ + s_;                                 \
  } while (0)

  v2f w6[6];
  #pragma unroll
  for (int i = 0; i < 6; ++i) RPAIR(w6[i], acc[2*i], acc[2*i+1], b5, 32);
  v2f X0, X1, X2;
  RPAIR(X0, w6[0], w6[1], b4, 16);
  RPAIR(X1, w6[2], w6[3], b4, 16);
  RPAIR(X2, w6[4], w6[5], b4, 16);
  v2f Y0, Y1;
  RPAIR(Y0, X0, X1, b3, 8);
  { v2f s_; s_.x = __shfl_xor(X2.x, 8); s_.y = __shfl_xor(X2.y, 8); Y1 = X2 + s_; }
  v2f Z;
  RPAIR(Z, Y0, Y1, b2, 4);
  { v2f s_; s_.x = __shfl_xor(Z.x, 2); s_.y = __shfl_xor(Z.y, 2); Z = Z + s_; }
  { v2f s_; s_.x = __shfl_xor(Z.x, 1); s_.y = __shfl_xor(Z.y, 1); Z = Z + s_; }
#undef RPAIR

  const int pp = b2 ? (8 + 2 * b4 + b5) : (4 * b3 + 2 * b4 + b5);
  if (((lane & 3) == 0) && (b2 == 0 || b3 == 0)) {
    const int p = p0 + pp;
    out[((p * 4 + c) * 32 + r) * 3 + e] = make_float2(Z.x, Z.y);
  }
}

// ---------------------------------------------------------------------------
extern "C" void kernel_launch(void* const* d_in, const int* in_sizes, int n_in,
                              void* d_out, int out_size, void* d_ws, size_t ws_size,
                              hipStream_t stream) {
  const float2* sing  = (const float2*)d_in[0];
  const float2* smap  = (const float2*)d_in[1];
  const float*  ktraj = (const float*)d_in[2];
  const float*  ur    = (const float*)d_in[3];
  const int*    zbin  = (const int*)d_in[4];
  // d_in[5] = dc, unused in forward

  float2* ex2  = (float2*)d_ws;          // 811 KB
  float2* imgw = ex2 + EXG2_F2;          // 12.6 MB
  float2* out  = (float2*)d_out;

  precompute_imgw<<<NPIX / 4, 256, 0, stream>>>(sing, smap, ur, zbin, ktraj, ex2, imgw);
  nufft_points<<<NRO * NEC * 2, 256, 0, stream>>>(ktraj, ex2, imgw, out);
}

// Round 2
// 92.096 us; speedup vs baseline: 1.0634x; 1.0411x over previous
//
#include <hip/hip_runtime.h>
#include <math.h>

// Dims
#define IMG 64
#define NPIX 4096      // 64*64 pixels, px = ix*64 + iy
#define NSLICE 16
#define NCOIL 4
#define NSING 4
#define NECHO 3
#define NRO 32
#define NPT 96
#define NEC 12         // NECHO*NCOIL after ur-contraction

typedef float v2f __attribute__((ext_vector_type(2)));

// ws layout: ex2 table [32r][33k][96p] float2 (811 KB), then imgw [32r][12ec][4096px] float2 (12.6 MB)
// ex2[r][k][p] = exp(-i*k*w0(r,p)) for k=1..31 ; k=0 slot holds exp(+32i*w0) (the x=0 special)
#define EXG2_F2 (NRO * 33 * NPT)          // 101376 float2

// ---------------------------------------------------------------------------
// Kernel A: imgw[r][ec][px] = sum_n ur[r,n] * DFTz(sign * sc * sm)[n,e,c, zb[r]]
// R7: LDS bank-conflict fixes. All old strides were multiples of 32 dwords:
//  - f_sh row stride 16 float2 (32 dwords) made every frow[k] write a 48-way
//    conflict (all lanes -> bank 2k) and contraction reads ~16-way. Pad to 17.
//  - sm_sh [pxl][c*16+z] made reads bank=2z for all (pxl,c): 16-way. New
//    layout [pxl][z*4+c] stride 68 -> 16 distinct banks, conflict-free.
// ---------------------------------------------------------------------------
__global__ __launch_bounds__(256) void precompute_imgw(
    const float2* __restrict__ sing,   // [4096px][16z][4n][3e]
    const float2* __restrict__ smap,   // [4c][4096px][16z]
    const float*  __restrict__ ur,     // [32][4]
    const int*    __restrict__ zb,     // [32]
    const float*  __restrict__ kt,     // [32][96][2]
    float2* __restrict__ ex2,          // [32][33][96]
    float2* __restrict__ imgw)         // [32][12][4096]
{
  __shared__ float2 sc_sh[4 * 192];     // [pxl][z*12 + s]
  __shared__ float2 sm_sh[4 * 68];      // [pxl][z*4 + c]  (stride 68 = 64 + 4 pad)
  __shared__ float2 f_sh[4 * 48 * 17];  // [pxl][s*4+c][kz] stride 17 (pad)  26 KB
  __shared__ float  ur_sh[128];
  __shared__ int    zb_sh[32];

  const int t   = threadIdx.x;
  const int px0 = blockIdx.x * 4;

  // side job: phase table (32*33*96 = 101376 = 396 blocks * 256 threads)
  if (blockIdx.x < 396) {
    int g = blockIdx.x * 256 + t;
    int p = g % 96;
    int k = (g / 96) % 33;
    int r = g / (96 * 33);
    float w0 = kt[(r * 96 + p) * 2];
    float ang = (k == 0) ? (32.0f * w0) : (-(float)k * w0);
    float s_, c_;
    __sincosf(ang, &s_, &c_);
    ex2[g] = make_float2(c_, s_);
  }

  // stage inputs (coalesced)
  for (int j = t; j < 768; j += 256) sc_sh[j] = sing[px0 * 192 + j];
  {
    int c = t >> 6, pxl = (t >> 4) & 3, z = t & 15;
    sm_sh[pxl * 68 + z * 4 + c] = smap[c * 65536 + (px0 + pxl) * 16 + z];
  }
  if (t < 128) ur_sh[t] = ur[t];
  if (t < 32)  zb_sh[t] = zb[t];
  __syncthreads();

  const int pxl = t >> 6, lane = t & 63;
  const int s = lane >> 2, c = lane & 3;

  // W16[m] = exp(-2*pi*i*m/16)
  const float wr[16] = { 1.f,  0.92387953f,  0.70710678f,  0.38268343f,
                         0.f, -0.38268343f, -0.70710678f, -0.92387953f,
                        -1.f, -0.92387953f, -0.70710678f, -0.38268343f,
                         0.f,  0.38268343f,  0.70710678f,  0.92387953f };
  const float wi_fix[16] = { 0.f, -0.38268343f, -0.70710678f, -0.92387953f,
                        -1.f, -0.92387953f, -0.70710678f, -0.38268343f,
                         0.f,  0.38268343f,  0.70710678f,  0.92387953f,
                         1.f,  0.92387953f,  0.70710678f,  0.38268343f };

  if (lane < 48) {
    float br[16], bi[16];
    #pragma unroll
    for (int z = 0; z < 16; ++z) {
      float2 a = sc_sh[pxl * 192 + z * 12 + s];
      float2 m = sm_sh[pxl * 68 + z * 4 + c];
      float sg = (z & 1) ? -1.f : 1.f;
      br[z] = sg * (a.x * m.x - a.y * m.y);
      bi[z] = sg * (a.x * m.y + a.y * m.x);
    }
    // f[kz] = E[kz&7] +/- W16[kz&7]*O[kz&7];  E/O = DFT8 of even/odd z
    float Er[8], Ei[8], Or[8], Oi[8];
    #pragma unroll
    for (int k = 0; k < 8; ++k) {
      float er = 0.f, ei = 0.f, pr = 0.f, pi = 0.f;
      #pragma unroll
      for (int m = 0; m < 8; ++m) {
        const int idx = (2 * k * m) & 15;
        er = fmaf(br[2*m],    wr[idx], er); er = fmaf(-bi[2*m],   wi_fix[idx], er);
        ei = fmaf(br[2*m],    wi_fix[idx], ei); ei = fmaf( bi[2*m],   wr[idx], ei);
        pr = fmaf(br[2*m+1],  wr[idx], pr); pr = fmaf(-bi[2*m+1], wi_fix[idx], pr);
        pi = fmaf(br[2*m+1],  wi_fix[idx], pi); pi = fmaf( bi[2*m+1], wr[idx], pi);
      }
      Er[k] = er; Ei[k] = ei; Or[k] = pr; Oi[k] = pi;
    }
    float2* frow = &f_sh[(pxl * 48 + s * 4 + c) * 17];
    #pragma unroll
    for (int k = 0; k < 8; ++k) {
      float tr = Or[k] * wr[k] - Oi[k] * wi_fix[k];
      float ti = Or[k] * wi_fix[k] + Oi[k] * wr[k];
      frow[k]     = make_float2(Er[k] + tr, Ei[k] + ti);
      frow[k + 8] = make_float2(Er[k] - tr, Ei[k] - ti);
    }
  }
  __syncthreads();

  // contraction + store: 1536 outputs (4 px * 384 rc), 6 per thread
  for (int j = t; j < 1536; j += 256) {
    int rc  = j >> 2;       // r*12 + ec
    int pl  = j & 3;
    int r   = rc / 12, ec = rc - r * 12;
    int e   = ec >> 2, cc = ec & 3;
    int kz  = zb_sh[r];
    float vr = 0.f, vi = 0.f;
    #pragma unroll
    for (int n = 0; n < 4; ++n) {
      float u  = ur_sh[r * 4 + n];
      float2 f = f_sh[(pl * 48 + (n * 3 + e) * 4 + cc) * 17 + kz];
      vr = fmaf(u, f.x, vr);
      vi = fmaf(u, f.y, vi);
    }
    imgw[rc * 4096 + px0 + pl] = make_float2(vr, vi);
  }
}

// ---------------------------------------------------------------------------
// Kernel B: one block (256 thr = 4 waves) per (r,ec,ps). Conjugate-folded
// NUFFT. R7 changes vs R6:
//  - ev reads moved OFF the LDS pipe: the ex2 addresses are wave-uniform
//    (p0l is per-wave), so read them directly from global with a
//    readfirstlane-forced uniform base -> scalar (SMEM) loads, sK$-cached.
//    Hot loop is now 1 DS instr per k (the per-lane folded-w b128) + 6
//    uniform loads + 24 pk_fma.
//  - ex_sh staging deleted (12.4 KB LDS and one prologue pass gone).
// ---------------------------------------------------------------------------
__global__ __launch_bounds__(256, 3) void nufft_points(
    const float*  __restrict__ kt,     // [32][96][2]
    const float2* __restrict__ ex2,    // [32][33][96]
    const float2* __restrict__ imgw,   // [32][12][4096]
    float2* __restrict__ out)          // [96][4][32][3]
{
  __shared__ float4 w2_sh[31 * 64];            // folded pairs, 31 KB
  __shared__ float2 w0_sh[64];                 // x = 0 row (k=32 special)
  __shared__ float2 w32_sh[64];                // x = 32 row (k=0 special)

  const int bid = blockIdx.x;          // 768 = 32r * 12ec * 2ps
  const int r   = bid & 31;
  const int ec  = (bid >> 5) % 12;
  const int ps  = bid / 384;
  const int e   = ec >> 2, c = ec & 3;
  const int t    = threadIdx.x;
  const int lane = t & 63;
  const int p0l  = (t >> 6) * 12;      // local point base (0,12,24,36)
  const int p0   = ps * 48 + p0l;      // global point base

  // wave-uniform base into ex2: eg[k*96 + pp] is this wave's phase row.
  // readfirstlane makes the base provably SGPR-uniform -> scalar loads.
  const int ubase = __builtin_amdgcn_readfirstlane(r * (33 * 96) + ps * 48 + p0l);
  const float2* __restrict__ eg = ex2 + ubase;

  // prefetch w1 for the epilogue (lane-uniform broadcast loads)
  float w1v[12];
  #pragma unroll
  for (int pp = 0; pp < 12; ++pp) w1v[pp] = kt[(r * 96 + p0 + pp) * 2 + 1];

  const float2* __restrict__ wsrc = imgw + (r * 12 + ec) * 4096;

  // stage the two unpaired rows (x=0 and x=32)
  if (t < 128) {
    int which = t >> 6, y = t & 63;
    float2 v = wsrc[which * 32 * 64 + y];
    if (which == 0) w0_sh[y] = v; else w32_sh[y] = v;
  }
  // conjugate-fold directly from global into interleaved (sxy,dyx) float4s
  for (int idx = t; idx < 31 * 64; idx += 256) {
    int k = 1 + (idx >> 6), y = idx & 63;
    float2 wa = wsrc[(32 + k) * 64 + y];
    float2 wb = wsrc[(32 - k) * 64 + y];
    w2_sh[idx] = make_float4(wa.x + wb.x, wa.y + wb.y,
                             -(wa.y - wb.y), wa.x - wb.x);
  }
  __syncthreads();

  // seed: acc[pp] = w[x=32] + w[x=0] * e^{+32i w0(p)}   (k=0 row of eg)
  v2f acc[12];
  {
    float2 w0v = w0_sh[lane];
    float2 w32 = w32_sh[lane];
    const float4* e40 = (const float4*)eg;     // 16B-aligned (p0l*8 % 16 == 0)
    #pragma unroll
    for (int pq = 0; pq < 6; ++pq) {
      float4 e2 = e40[pq];
      acc[2*pq].x   = w32.x + w0v.x * e2.x - w0v.y * e2.y;
      acc[2*pq].y   = w32.y + w0v.x * e2.y + w0v.y * e2.x;
      acc[2*pq+1].x = w32.x + w0v.x * e2.z - w0v.y * e2.w;
      acc[2*pq+1].y = w32.y + w0v.x * e2.w + w0v.y * e2.z;
    }
  }

  // hot loop: 1 DS instr per k + 6 uniform (scalar) loads + 24 pk_fma
  #pragma unroll 2
  for (int k = 1; k < 32; ++k) {
    float4 wv = w2_sh[(k - 1) * 64 + lane];
    v2f sxy = { wv.x, wv.y };
    v2f dyx = { wv.z, wv.w };
    const float4* e4 = (const float4*)(eg + k * 96);
    #pragma unroll
    for (int pq = 0; pq < 6; ++pq) {
      float4 e2 = e4[pq];
      acc[2*pq]   = __builtin_elementwise_fma(sxy, (v2f)(e2.x), acc[2*pq]);
      acc[2*pq]   = __builtin_elementwise_fma(dyx, (v2f)(e2.y), acc[2*pq]);
      acc[2*pq+1] = __builtin_elementwise_fma(sxy, (v2f)(e2.z), acc[2*pq+1]);
      acc[2*pq+1] = __builtin_elementwise_fma(dyx, (v2f)(e2.w), acc[2*pq+1]);
    }
  }

  // epilogue: rotate by ey(p, lane)
  const float yy = (float)(lane - 32);
  #pragma unroll
  for (int pp = 0; pp < 12; ++pp) {
    float es, ec_;
    __sincosf(-w1v[pp] * yy, &es, &ec_);
    v2f tv;
    tv.x = acc[pp].x * ec_ - acc[pp].y * es;
    tv.y = acc[pp].x * es  + acc[pp].y * ec_;
    acc[pp] = tv;
  }

  // reduce-scatter across 64 lanes. At each level, select-before-shuffle:
  //   x = bit ? B : A; y = bit ? A : B; out = x + shfl_xor(y, off)
  // sums the lane-pair while halving live values. Value identity after L4:
  //   pp = b2 ? (8 + 2*b4 + b5) : (4*b3 + 2*b4 + b5)
  const int b5 = (lane >> 5) & 1, b4 = (lane >> 4) & 1;
  const int b3 = (lane >> 3) & 1, b2 = (lane >> 2) & 1;

#define RPAIR(OUT, A, B, BIT, OFF) do {            \
    v2f x_ = (BIT) ? (B) : (A);                    \
    v2f y_ = (BIT) ? (A) : (B);                    \
    v2f s_;                                        \
    s_.x = __shfl_xor(y_.x, OFF);                  \
    s_.y = __shfl_xor(y_.y, OFF);                  \
    OUT = x_ + s_;                                 \
  } while (0)

  v2f w6[6];
  #pragma unroll
  for (int i = 0; i < 6; ++i) RPAIR(w6[i], acc[2*i], acc[2*i+1], b5, 32);
  v2f X0, X1, X2;
  RPAIR(X0, w6[0], w6[1], b4, 16);
  RPAIR(X1, w6[2], w6[3], b4, 16);
  RPAIR(X2, w6[4], w6[5], b4, 16);
  v2f Y0, Y1;
  RPAIR(Y0, X0, X1, b3, 8);
  { v2f s_; s_.x = __shfl_xor(X2.x, 8); s_.y = __shfl_xor(X2.y, 8); Y1 = X2 + s_; }
  v2f Z;
  RPAIR(Z, Y0, Y1, b2, 4);
  { v2f s_; s_.x = __shfl_xor(Z.x, 2); s_.y = __shfl_xor(Z.y, 2); Z = Z + s_; }
  { v2f s_; s_.x = __shfl_xor(Z.x, 1); s_.y = __shfl_xor(Z.y, 1); Z = Z + s_; }
#undef RPAIR

  const int pp = b2 ? (8 + 2 * b4 + b5) : (4 * b3 + 2 * b4 + b5);
  if (((lane & 3) == 0) && (b2 == 0 || b3 == 0)) {
    const int p = p0 + pp;
    out[((p * 4 + c) * 32 + r) * 3 + e] = make_float2(Z.x, Z.y);
  }
}

// ---------------------------------------------------------------------------
extern "C" void kernel_launch(void* const* d_in, const int* in_sizes, int n_in,
                              void* d_out, int out_size, void* d_ws, size_t ws_size,
                              hipStream_t stream) {
  const float2* sing  = (const float2*)d_in[0];
  const float2* smap  = (const float2*)d_in[1];
  const float*  ktraj = (const float*)d_in[2];
  const float*  ur    = (const float*)d_in[3];
  const int*    zbin  = (const int*)d_in[4];
  // d_in[5] = dc, unused in forward

  float2* ex2  = (float2*)d_ws;          // 811 KB
  float2* imgw = ex2 + EXG2_F2;          // 12.6 MB
  float2* out  = (float2*)d_out;

  precompute_imgw<<<NPIX / 4, 256, 0, stream>>>(sing, smap, ur, zbin, ktraj, ex2, imgw);
  nufft_points<<<NRO * NEC * 2, 256, 0, stream>>>(ktraj, ex2, imgw, out);
}

// Round 4
// 91.736 us; speedup vs baseline: 1.0676x; 1.0039x over previous
//
#include <hip/hip_runtime.h>
#include <math.h>

// Dims
#define IMG 64
#define NPIX 4096      // 64*64 pixels, px = ix*64 + iy
#define NSLICE 16
#define NCOIL 4
#define NSING 4
#define NECHO 3
#define NRO 32
#define NPT 96
#define NEC 12         // NECHO*NCOIL after ur-contraction

typedef float v2f __attribute__((ext_vector_type(2)));

// ws layout: ex2 table [32r][33k][96p] float2 (811 KB), then imgw [32r][12ec][4096px] float2 (12.6 MB)
// ex2[r][k][p] = exp(-i*k*w0(r,p)) for k=1..31 ; k=0 slot holds exp(+32i*w0) (the x=0 special)
#define EXG2_F2 (NRO * 33 * NPT)          // 101376 float2

// ---------------------------------------------------------------------------
// Kernel A: imgw[r][ec][px] = sum_n ur[r,n] * DFTz(sign * sc * sm)[n,e,c, zb[r]]
// R9 = R7 + side-job spread: the ex2 phase table (101376 = 1024 blocks * 99)
// is built 99 contiguous elements per block (was 256 elems on blocks 0..395),
// trimming the critical-path tail. NOTE (R8 lesson): A and B must stay
// separate dispatches — kernel B reads ex2 through the SCALAR cache, which is
// only safe across a kernel boundary (sK$ not coherent with vector stores).
// ---------------------------------------------------------------------------
__global__ __launch_bounds__(256) void precompute_imgw(
    const float2* __restrict__ sing,   // [4096px][16z][4n][3e]
    const float2* __restrict__ smap,   // [4c][4096px][16z]
    const float*  __restrict__ ur,     // [32][4]
    const int*    __restrict__ zb,     // [32]
    const float*  __restrict__ kt,     // [32][96][2]
    float2* __restrict__ ex2,          // [32][33][96]
    float2* __restrict__ imgw)         // [32][12][4096]
{
  __shared__ float2 sc_sh[4 * 192];     // [pxl][z*12 + s]
  __shared__ float2 sm_sh[4 * 68];      // [pxl][z*4 + c]  (stride 68 = 64 + 4 pad)
  __shared__ float2 f_sh[4 * 48 * 17];  // [pxl][s*4+c][kz] stride 17 (pad)  26 KB
  __shared__ float  ur_sh[128];
  __shared__ int    zb_sh[32];

  const int t   = threadIdx.x;
  const int px0 = blockIdx.x * 4;

  // side job: phase table, 99 contiguous elements per block (99*1024 = 101376)
  if (t < 99) {
    int g = blockIdx.x * 99 + t;
    int p = g % 96;
    int k = (g / 96) % 33;
    int r = g / (96 * 33);
    float w0 = kt[(r * 96 + p) * 2];
    float ang = (k == 0) ? (32.0f * w0) : (-(float)k * w0);
    float s_, c_;
    __sincosf(ang, &s_, &c_);
    ex2[g] = make_float2(c_, s_);
  }

  // stage inputs (coalesced; sing as float4)
  {
    const float4* ssrc = (const float4*)(sing + px0 * 192);
    float4* sdst = (float4*)sc_sh;
    sdst[t] = ssrc[t];
    if (t < 128) sdst[256 + t] = ssrc[256 + t];
  }
  {
    int c = t >> 6, pxl = (t >> 4) & 3, z = t & 15;
    sm_sh[pxl * 68 + z * 4 + c] = smap[c * 65536 + (px0 + pxl) * 16 + z];
  }
  if (t < 128) ur_sh[t] = ur[t];
  if (t < 32)  zb_sh[t] = zb[t];
  __syncthreads();

  const int pxl = t >> 6, lane = t & 63;
  const int s = lane >> 2, c = lane & 3;

  // W16[m] = exp(-2*pi*i*m/16)
  const float wr[16] = { 1.f,  0.92387953f,  0.70710678f,  0.38268343f,
                         0.f, -0.38268343f, -0.70710678f, -0.92387953f,
                        -1.f, -0.92387953f, -0.70710678f, -0.38268343f,
                         0.f,  0.38268343f,  0.70710678f,  0.92387953f };
  const float wi_fix[16] = { 0.f, -0.38268343f, -0.70710678f, -0.92387953f,
                        -1.f, -0.92387953f, -0.70710678f, -0.38268343f,
                         0.f,  0.38268343f,  0.70710678f,  0.92387953f,
                         1.f,  0.92387953f,  0.70710678f,  0.38268343f };

  if (lane < 48) {
    float br[16], bi[16];
    #pragma unroll
    for (int z = 0; z < 16; ++z) {
      float2 a = sc_sh[pxl * 192 + z * 12 + s];
      float2 m = sm_sh[pxl * 68 + z * 4 + c];
      float sg = (z & 1) ? -1.f : 1.f;
      br[z] = sg * (a.x * m.x - a.y * m.y);
      bi[z] = sg * (a.x * m.y + a.y * m.x);
    }
    // f[kz] = E[kz&7] +/- W16[kz&7]*O[kz&7];  E/O = DFT8 of even/odd z
    float Er[8], Ei[8], Or[8], Oi[8];
    #pragma unroll
    for (int k = 0; k < 8; ++k) {
      float er = 0.f, ei = 0.f, pr = 0.f, pi = 0.f;
      #pragma unroll
      for (int m = 0; m < 8; ++m) {
        const int idx = (2 * k * m) & 15;
        er = fmaf(br[2*m],    wr[idx], er); er = fmaf(-bi[2*m],   wi_fix[idx], er);
        ei = fmaf(br[2*m],    wi_fix[idx], ei); ei = fmaf( bi[2*m],   wr[idx], ei);
        pr = fmaf(br[2*m+1],  wr[idx], pr); pr = fmaf(-bi[2*m+1], wi_fix[idx], pr);
        pi = fmaf(br[2*m+1],  wi_fix[idx], pi); pi = fmaf( bi[2*m+1], wr[idx], pi);
      }
      Er[k] = er; Ei[k] = ei; Or[k] = pr; Oi[k] = pi;
    }
    float2* frow = &f_sh[(pxl * 48 + s * 4 + c) * 17];
    #pragma unroll
    for (int k = 0; k < 8; ++k) {
      float tr = Or[k] * wr[k] - Oi[k] * wi_fix[k];
      float ti = Or[k] * wi_fix[k] + Oi[k] * wr[k];
      frow[k]     = make_float2(Er[k] + tr, Ei[k] + ti);
      frow[k + 8] = make_float2(Er[k] - tr, Ei[k] - ti);
    }
  }
  __syncthreads();

  // contraction + store: 1536 outputs (4 px * 384 rc), 6 per thread
  for (int j = t; j < 1536; j += 256) {
    int rc  = j >> 2;       // r*12 + ec
    int pl  = j & 3;
    int r   = rc / 12, ec = rc - r * 12;
    int e   = ec >> 2, cc = ec & 3;
    int kz  = zb_sh[r];
    float vr = 0.f, vi = 0.f;
    #pragma unroll
    for (int n = 0; n < 4; ++n) {
      float u  = ur_sh[r * 4 + n];
      float2 f = f_sh[(pl * 48 + (n * 3 + e) * 4 + cc) * 17 + kz];
      vr = fmaf(u, f.x, vr);
      vi = fmaf(u, f.y, vi);
    }
    imgw[rc * 4096 + px0 + pl] = make_float2(vr, vi);
  }
}

// ---------------------------------------------------------------------------
// Kernel B: one block (256 thr = 4 waves) per (r,ec,ps). Conjugate-folded
// NUFFT. R9 = R7 + float4 source reads in the fold staging (each thread folds
// 2 adjacent y; halves staging load instructions). Hot loop unchanged:
// 1 DS instr per k (per-lane folded-w b128) + 6 uniform scalar loads from
// global ex2 (sK$-cached; safe ONLY because ex2 was written by the previous
// dispatch) + 24 pk_fma.
// ---------------------------------------------------------------------------
__global__ __launch_bounds__(256, 3) void nufft_points(
    const float*  __restrict__ kt,     // [32][96][2]
    const float2* __restrict__ ex2,    // [32][33][96]
    const float2* __restrict__ imgw,   // [32][12][4096]
    float2* __restrict__ out)          // [96][4][32][3]
{
  __shared__ float4 w2_sh[31 * 64];            // folded pairs, 31 KB
  __shared__ float2 w0_sh[64];                 // x = 0 row (k=32 special)
  __shared__ float2 w32_sh[64];                // x = 32 row (k=0 special)

  const int bid = blockIdx.x;          // 768 = 32r * 12ec * 2ps
  const int r   = bid & 31;
  const int ec  = (bid >> 5) % 12;
  const int ps  = bid / 384;
  const int e   = ec >> 2, c = ec & 3;
  const int t    = threadIdx.x;
  const int lane = t & 63;
  const int p0l  = (t >> 6) * 12;      // local point base (0,12,24,36)
  const int p0   = ps * 48 + p0l;      // global point base

  // wave-uniform base into ex2: eg[k*96 + pp] is this wave's phase row.
  // readfirstlane makes the base provably SGPR-uniform -> scalar loads.
  const int ubase = __builtin_amdgcn_readfirstlane(r * (33 * 96) + ps * 48 + p0l);
  const float2* __restrict__ eg = ex2 + ubase;

  // prefetch w1 for the epilogue (lane-uniform broadcast loads)
  float w1v[12];
  #pragma unroll
  for (int pp = 0; pp < 12; ++pp) w1v[pp] = kt[(r * 96 + p0 + pp) * 2 + 1];

  const float2* __restrict__ wsrc = imgw + (r * 12 + ec) * 4096;

  // stage the two unpaired rows (x=0 and x=32)
  if (t < 128) {
    int which = t >> 6, y = t & 63;
    float2 v = wsrc[which * 32 * 64 + y];
    if (which == 0) w0_sh[y] = v; else w32_sh[y] = v;
  }
  // conjugate-fold directly from global into interleaved (sxy,dyx) float4s.
  // float4 source reads: each thread folds 2 adjacent y.
  for (int idx = t; idx < 31 * 32; idx += 256) {
    int k = 1 + (idx >> 5), y2 = idx & 31;
    float4 wa2 = *(const float4*)&wsrc[(32 + k) * 64 + 2 * y2];
    float4 wb2 = *(const float4*)&wsrc[(32 - k) * 64 + 2 * y2];
    w2_sh[(k - 1) * 64 + 2 * y2]     = make_float4(wa2.x + wb2.x, wa2.y + wb2.y,
                                                   -(wa2.y - wb2.y), wa2.x - wb2.x);
    w2_sh[(k - 1) * 64 + 2 * y2 + 1] = make_float4(wa2.z + wb2.z, wa2.w + wb2.w,
                                                   -(wa2.w - wb2.w), wa2.z - wb2.z);
  }
  __syncthreads();

  // seed: acc[pp] = w[x=32] + w[x=0] * e^{+32i w0(p)}   (k=0 row of eg)
  v2f acc[12];
  {
    float2 w0v = w0_sh[lane];
    float2 w32 = w32_sh[lane];
    const float4* e40 = (const float4*)eg;     // 16B-aligned (p0l*8 % 16 == 0)
    #pragma unroll
    for (int pq = 0; pq < 6; ++pq) {
      float4 e2 = e40[pq];
      acc[2*pq].x   = w32.x + w0v.x * e2.x - w0v.y * e2.y;
      acc[2*pq].y   = w32.y + w0v.x * e2.y + w0v.y * e2.x;
      acc[2*pq+1].x = w32.x + w0v.x * e2.z - w0v.y * e2.w;
      acc[2*pq+1].y = w32.y + w0v.x * e2.w + w0v.y * e2.z;
    }
  }

  // hot loop: 1 DS instr per k + 6 uniform (scalar) loads + 24 pk_fma
  #pragma unroll 2
  for (int k = 1; k < 32; ++k) {
    float4 wv = w2_sh[(k - 1) * 64 + lane];
    v2f sxy = { wv.x, wv.y };
    v2f dyx = { wv.z, wv.w };
    const float4* e4 = (const float4*)(eg + k * 96);
    #pragma unroll
    for (int pq = 0; pq < 6; ++pq) {
      float4 e2 = e4[pq];
      acc[2*pq]   = __builtin_elementwise_fma(sxy, (v2f)(e2.x), acc[2*pq]);
      acc[2*pq]   = __builtin_elementwise_fma(dyx, (v2f)(e2.y), acc[2*pq]);
      acc[2*pq+1] = __builtin_elementwise_fma(sxy, (v2f)(e2.z), acc[2*pq+1]);
      acc[2*pq+1] = __builtin_elementwise_fma(dyx, (v2f)(e2.w), acc[2*pq+1]);
    }
  }

  // epilogue: rotate by ey(p, lane)
  const float yy = (float)(lane - 32);
  #pragma unroll
  for (int pp = 0; pp < 12; ++pp) {
    float es, ec_;
    __sincosf(-w1v[pp] * yy, &es, &ec_);
    v2f tv;
    tv.x = acc[pp].x * ec_ - acc[pp].y * es;
    tv.y = acc[pp].x * es  + acc[pp].y * ec_;
    acc[pp] = tv;
  }

  // reduce-scatter across 64 lanes. At each level, select-before-shuffle:
  //   x = bit ? B : A; y = bit ? A : B; out = x + shfl_xor(y, off)
  // sums the lane-pair while halving live values. Value identity after L4:
  //   pp = b2 ? (8 + 2*b4 + b5) : (4*b3 + 2*b4 + b5)
  const int b5 = (lane >> 5) & 1, b4 = (lane >> 4) & 1;
  const int b3 = (lane >> 3) & 1, b2 = (lane >> 2) & 1;

#define RPAIR(OUT, A, B, BIT, OFF) do {            \
    v2f x_ = (BIT) ? (B) : (A);                    \
    v2f y_ = (BIT) ? (A) : (B);                    \
    v2f s_;                                        \
    s_.x = __shfl_xor(y_.x, OFF);                  \
    s_.y = __shfl_xor(y_.y, OFF);                  \
    OUT = x_ + s_;                                 \
  } while (0)

  v2f w6[6];
  #pragma unroll
  for (int i = 0; i < 6; ++i) RPAIR(w6[i], acc[2*i], acc[2*i+1], b5, 32);
  v2f X0, X1, X2;
  RPAIR(X0, w6[0], w6[1], b4, 16);
  RPAIR(X1, w6[2], w6[3], b4, 16);
  RPAIR(X2, w6[4], w6[5], b4, 16);
  v2f Y0, Y1;
  RPAIR(Y0, X0, X1, b3, 8);
  { v2f s_; s_.x = __shfl_xor(X2.x, 8); s_.y = __shfl_xor(X2.y, 8); Y1 = X2 + s_; }
  v2f Z;
  RPAIR(Z, Y0, Y1, b2, 4);
  { v2f s_; s_.x = __shfl_xor(Z.x, 2); s_.y = __shfl_xor(Z.y, 2); Z = Z + s_; }
  { v2f s_; s_.x = __shfl_xor(Z.x, 1); s_.y = __shfl_xor(Z.y, 1); Z = Z + s_; }
#undef RPAIR

  const int pp = b2 ? (8 + 2 * b4 + b5) : (4 * b3 + 2 * b4 + b5);
  if (((lane & 3) == 0) && (b2 == 0 || b3 == 0)) {
    const int p = p0 + pp;
    out[((p * 4 + c) * 32 + r) * 3 + e] = make_float2(Z.x, Z.y);
  }
}

// ---------------------------------------------------------------------------
extern "C" void kernel_launch(void* const* d_in, const int* in_sizes, int n_in,
                              void* d_out, int out_size, void* d_ws, size_t ws_size,
                              hipStream_t stream) {
  const float2* sing  = (const float2*)d_in[0];
  const float2* smap  = (const float2*)d_in[1];
  const float*  ktraj = (const float*)d_in[2];
  const float*  ur    = (const float*)d_in[3];
  const int*    zbin  = (const int*)d_in[4];
  // d_in[5] = dc, unused in forward

  float2* ex2  = (float2*)d_ws;          // 811 KB
  float2* imgw = ex2 + EXG2_F2;          // 12.6 MB
  float2* out  = (float2*)d_out;

  precompute_imgw<<<NPIX / 4, 256, 0, stream>>>(sing, smap, ur, zbin, ktraj, ex2, imgw);
  nufft_points<<<NRO * NEC * 2, 256, 0, stream>>>(ktraj, ex2, imgw, out);
}